// Round 3
// baseline (253.461 us; speedup 1.0000x reference)
//
#include <hip/hip_runtime.h>
#include <math.h>

// EnergySRB, R8: FORCE the load pipeline.
// R7 post-mortem: compiler sank the prefetch (VGPR 24, loads re-serialized)
// because nothing pinned instruction order inside the single basic block.
// R5/R6/R7 all sit at 81-86us = 2.26 TB/s effective: latency-bound with ~1
// outstanding wave-load per wave (Little's law: ~3.5Kcyc loaded latency).
// R8: depth-2 register prefetch (A/B/C buffers) with
// __builtin_amdgcn_sched_barrier(0) between the prefetch-issue cluster and
// the body - the compiler may NOT move loads across it. vmcnt stays counted
// (body waits only for the oldest 3 loads; 6 newer stay in flight).
// Math bit-identical to R6/R7. LDS still exactly 80KB -> 2 blocks/CU.

#define NT        1024
#define NBLK      512
#define SCALE_F   134217728.0f              // 2^27
#define INV_SCALE 7.450580596923828125e-9   // 2^-27, exact in double

// ---------------------------------------------------------------------------
// pack species (values 0..3) into 2-bit words. 262144 atoms -> 64KB.
__global__ void pack_species_kernel(const int* __restrict__ sp,
                                    unsigned* __restrict__ packed, int nwords) {
    int w = blockIdx.x * blockDim.x + threadIdx.x;
    if (w >= nwords) return;
    const int4* p4 = (const int4*)(sp + (w << 4));
    int4 a = p4[0], b = p4[1], c = p4[2], d = p4[3];
    unsigned v =
        (unsigned)(a.x & 3)        | ((unsigned)(a.y & 3) << 2)  |
        ((unsigned)(a.z & 3) << 4) | ((unsigned)(a.w & 3) << 6)  |
        ((unsigned)(b.x & 3) << 8) | ((unsigned)(b.y & 3) << 10) |
        ((unsigned)(b.z & 3) << 12)| ((unsigned)(b.w & 3) << 14) |
        ((unsigned)(c.x & 3) << 16)| ((unsigned)(c.y & 3) << 18) |
        ((unsigned)(c.z & 3) << 20)| ((unsigned)(c.w & 3) << 22) |
        ((unsigned)(d.x & 3) << 24)| ((unsigned)(d.y & 3) << 26) |
        ((unsigned)(d.z & 3) << 28)| ((unsigned)(d.w & 3) << 30);
    packed[w] = v;
}

// ---------------------------------------------------------------------------
// init: species passthrough to out[0:n_species); zero the u64 accumulator.
__global__ void init_kernel(const int* __restrict__ species,
                            float* __restrict__ out,
                            unsigned long long* __restrict__ acc,
                            int n_species, int n_mol) {
    int i = blockIdx.x * blockDim.x + threadIdx.x;
    if (i < n_species) out[i] = (float)species[i];
    if (i < n_mol)     acc[i] = 0ull;
}

// ---------------------------------------------------------------------------
// Fused main kernel. LDS: exactly 80KB = 64KB packed species + 16KB u32 bins
// -> 2 blocks/CU (32 waves/CU). Table in wave registers via __shfl.
__global__ __launch_bounds__(NT, 8)
void srb_fused_u32(const unsigned* __restrict__ packed_ws,
                   const int* __restrict__ ai,     // [2, P]
                   const float* __restrict__ dist, // [P] angstrom
                   const float* __restrict__ pre_tab,   // 16 floats (negative)
                   const float* __restrict__ dfac_tab,  // 16 floats
                   unsigned long long* __restrict__ acc, // [n_mol]
                   int P, int mol_shift) {
    __shared__ unsigned packed[16384]; // 64KB: 2-bit species, all atoms
    __shared__ unsigned binsu[4096];   // 16KB: fixed-point per-mol sums

    const int t = threadIdx.x;
    for (int i = t; i < 4096; i += NT) binsu[i] = 0u;

    // register-resident table: lane L (of each wave) holds entry L&15.
    const float myPre  = -pre_tab[t & 15];   // magnitude, > 0
    const float myDfac =  dfac_tab[t & 15];

    {
        int4* dst = (int4*)packed;
        const int4* src = (const int4*)packed_ws;
        for (int i = t; i < 4096; i += NT) dst[i] = src[i];
    }
    __syncthreads();

    const float a2b   = (float)1.8897261258369282;
    const float rc    = (float)(5.2 * 1.8897261258369282);
    const float rcinv = (float)(1.0 / (5.2 * 1.8897261258369282));

    // 4 pairs per group; depth-2 register prefetch, order pinned by
    // sched_barrier(0) so the compiler cannot sink the loads.
    const int ng     = P >> 2;                 // groups of 4
    const int stride = (int)gridDim.x * NT;
    const int4*   v0 = (const int4*)ai;
    const int4*   v1 = (const int4*)(ai + P);
    const float4* dv = (const float4*)dist;

    int gA = (int)blockIdx.x * NT + t;
    int4 A0, A1; float4 AD;
    int4 B0, B1; float4 BD;
    bool haveA = (gA < ng);
    if (haveA) { A0 = v0[gA]; A1 = v1[gA]; AD = dv[gA]; }
    int gB = gA + stride;
    bool haveB = (gB < ng);
    if (haveB) { B0 = v0[gB]; B1 = v1[gB]; BD = dv[gB]; }
    int gC = gB + stride;

    #pragma unroll 1
    while (haveA) {
        // ---- issue prefetch for iteration k+2 (stays in flight) ----
        bool haveC = (gC < ng);
        int4 C0, C1; float4 CD;
        if (haveC) { C0 = v0[gC]; C1 = v1[gC]; CD = dv[gC]; }

        // HARD FENCE: nothing crosses. Loads above stay above the body;
        // body's vmcnt wait is counted (waits only the oldest 3 loads).
        __builtin_amdgcn_sched_barrier(0);

        // ---- body: iteration k (data loaded 2 iterations ago) ----
        unsigned a0[4] = { (unsigned)A0.x, (unsigned)A0.y,
                           (unsigned)A0.z, (unsigned)A0.w };
        unsigned a1[4] = { (unsigned)A1.x, (unsigned)A1.y,
                           (unsigned)A1.z, (unsigned)A1.w };
        float    dd[4] = { AD.x, AD.y, AD.z, AD.w };

        // Phase 1: all 8 species gathers in flight.
        unsigned w0[4], w1[4];
        #pragma unroll
        for (int k = 0; k < 4; ++k) w0[k] = packed[a0[k] >> 4];
        #pragma unroll
        for (int k = 0; k < 4; ++k) w1[k] = packed[a1[k] >> 4];

        // Phase 2: table lookup via wave shuffle (ds_bpermute).
        float pr[4], df[4];
        #pragma unroll
        for (int k = 0; k < 4; ++k) {
            unsigned s0 = (w0[k] >> ((a0[k] & 15u) << 1)) & 3u;
            unsigned s1 = (w1[k] >> ((a1[k] & 15u) << 1)) & 3u;
            int idx = (int)((s0 << 2) | s1);
            pr[k] = __shfl(myPre,  idx, 64);
            df[k] = __shfl(myDfac, idx, 64);
        }

        // Phase 3: 4 independent VALU chains (bit-identical to R6/R7).
        unsigned q[4];
        #pragma unroll
        for (int k = 0; k < 4; ++k) {
            float db  = dd[k] * a2b;
            float x   = db * rcinv;
            float arg = df[k] * db + (1.0f - 1.0f / (1.0f - x * x));
            float mag = pr[k] * __expf(arg);     // pr = |pre| > 0
            mag = (db < rc) ? mag : 0.0f;        // exact 0 beyond cutoff
            q[k] = (unsigned)(mag * SCALE_F);    // trunc; < 2^24 always
        }

        // Phase 4: 4 branchless atomics.
        #pragma unroll
        for (int k = 0; k < 4; ++k)
            atomicAdd(&binsu[a0[k] >> mol_shift], q[k]); // ds_add_u32

        // ---- rotate pipeline ----
        A0 = B0; A1 = B1; AD = BD; haveA = haveB;
        B0 = C0; B1 = C1; BD = CD; haveB = haveC;
        gB = gC; gC += stride;
    }

    __syncthreads();
    for (int i = t; i < 4096; i += NT) {
        unsigned v = binsu[i];
        if (v) atomicAdd(&acc[i], (unsigned long long)v); // native u64 atomic
    }
}

// ---------------------------------------------------------------------------
// final: out_e[m] = energies[m] - acc[m] * 2^-27  (exact in double)
__global__ void final_kernel(const unsigned long long* __restrict__ acc,
                             const float* __restrict__ energies,
                             float* __restrict__ out_e, int n_mol) {
    int m = blockIdx.x * blockDim.x + threadIdx.x;
    if (m < n_mol)
        out_e[m] = energies[m] - (float)((double)acc[m] * INV_SCALE);
}

// ---------------------------------------------------------------------------
// Fallback (ws too small): fused float-atomic path, out_e preset.
__global__ void init_out_fallback(const int* __restrict__ species,
                                  const float* __restrict__ energies,
                                  float* __restrict__ out,
                                  int n_species, int n_mol) {
    int i = blockIdx.x * blockDim.x + threadIdx.x;
    if (i < n_species) out[i] = (float)species[i];
    else if (i < n_species + n_mol) out[i] = energies[i - n_species];
}

__global__ __launch_bounds__(NT, 1)
void srb_fused_f32(const int* __restrict__ species,
                   const int* __restrict__ ai,
                   const float* __restrict__ dist,
                   const float* __restrict__ pre_tab,
                   const float* __restrict__ dfac_tab,
                   float* __restrict__ out_e,
                   int P, int mol_shift) {
    __shared__ unsigned packed[16384];
    __shared__ float bins[4096];
    __shared__ float2 tab[16];
    const int t = threadIdx.x;
    for (int i = t; i < 4096; i += NT) bins[i] = 0.0f;
    if (t < 16) tab[t] = make_float2(pre_tab[t], dfac_tab[t]);
    for (int w = t; w < 16384; w += NT) {
        const int4* p4 = (const int4*)(species + (w << 4));
        int4 a = p4[0], b = p4[1], c = p4[2], d = p4[3];
        unsigned v =
            (unsigned)(a.x & 3)        | ((unsigned)(a.y & 3) << 2)  |
            ((unsigned)(a.z & 3) << 4) | ((unsigned)(a.w & 3) << 6)  |
            ((unsigned)(b.x & 3) << 8) | ((unsigned)(b.y & 3) << 10) |
            ((unsigned)(b.z & 3) << 12)| ((unsigned)(b.w & 3) << 14) |
            ((unsigned)(c.x & 3) << 16)| ((unsigned)(c.y & 3) << 18) |
            ((unsigned)(c.z & 3) << 20)| ((unsigned)(c.w & 3) << 22) |
            ((unsigned)(d.x & 3) << 24)| ((unsigned)(d.y & 3) << 26) |
            ((unsigned)(d.z & 3) << 28)| ((unsigned)(d.w & 3) << 30);
        packed[w] = v;
    }
    __syncthreads();
    const float a2b   = (float)1.8897261258369282;
    const float rc    = (float)(5.2 * 1.8897261258369282);
    const float rcinv = (float)(1.0 / (5.2 * 1.8897261258369282));
    auto body = [&](int a0, int a1, float dang) {
        unsigned ua0 = (unsigned)a0, ua1 = (unsigned)a1;
        unsigned s0 = (packed[ua0 >> 4] >> ((ua0 & 15u) << 1)) & 3u;
        unsigned s1 = (packed[ua1 >> 4] >> ((ua1 & 15u) << 1)) & 3u;
        float2 td = tab[(s0 << 2) | s1];
        float db = dang * a2b;
        float x  = db * rcinv;
        float arg = td.y * db + (1.0f - 1.0f / (1.0f - x * x));
        float srb = td.x * __expf(arg);
        srb = (db < rc) ? srb : 0.0f;
        atomicAdd(&bins[ua0 >> mol_shift], srb);
    };
    const int nv = P >> 2, stride = (int)gridDim.x * NT;
    const int4* v0 = (const int4*)ai;
    const int4* v1 = (const int4*)(ai + P);
    const float4* dv = (const float4*)dist;
    for (int v = (int)blockIdx.x * NT + t; v < nv; v += stride) {
        int4 i0 = v0[v]; int4 i1 = v1[v]; float4 dd = dv[v];
        body(i0.x, i1.x, dd.x); body(i0.y, i1.y, dd.y);
        body(i0.z, i1.z, dd.z); body(i0.w, i1.w, dd.w);
    }
    __syncthreads();
    for (int i = t; i < 4096; i += NT) {
        float s = bins[i];
        if (s != 0.0f) atomicAdd(&out_e[i], s);
    }
}

// ---------------------------------------------------------------------------
extern "C" void kernel_launch(void* const* d_in, const int* in_sizes, int n_in,
                              void* d_out, int out_size, void* d_ws, size_t ws_size,
                              hipStream_t stream) {
    const int*   species  = (const int*)d_in[0];
    const float* energies = (const float*)d_in[1];
    const int*   ai       = (const int*)d_in[2];
    const float* dist     = (const float*)d_in[3];
    const float* pre_tab  = (const float*)d_in[4];
    const float* dfac_tab = (const float*)d_in[5];

    const int n_species = in_sizes[0];            // 262144
    const int n_mol     = in_sizes[1];            // 4096
    const int P         = in_sizes[3];            // 16777216
    const int n_atoms   = n_species / n_mol;      // 64

    int mol_shift = 0;
    while ((1 << mol_shift) < n_atoms) ++mol_shift; // 6

    float* out   = (float*)d_out;
    float* out_e = out + n_species;

    const int    nwords    = n_species / 16;              // 16384
    const size_t packed_sz = (size_t)nwords * 4;          // 64KB
    const size_t acc_sz    = (size_t)n_mol * 8;           // 32KB
    const size_t need      = packed_sz + acc_sz;

    if (ws_size >= need && (P & 3) == 0) {
        unsigned*           packed = (unsigned*)d_ws;
        unsigned long long* acc    = (unsigned long long*)((char*)d_ws + packed_sz);

        init_kernel<<<(n_species + 255) / 256, 256, 0, stream>>>(
            species, out, acc, n_species, n_mol);
        pack_species_kernel<<<(nwords + 255) / 256, 256, 0, stream>>>(
            species, packed, nwords);
        srb_fused_u32<<<NBLK, NT, 0, stream>>>(
            packed, ai, dist, pre_tab, dfac_tab, acc, P, mol_shift);
        final_kernel<<<(n_mol + 255) / 256, 256, 0, stream>>>(
            acc, energies, out_e, n_mol);
    } else {
        init_out_fallback<<<(n_species + n_mol + 255) / 256, 256, 0, stream>>>(
            species, energies, out, n_species, n_mol);
        srb_fused_f32<<<NBLK, NT, 0, stream>>>(
            species, ai, dist, pre_tab, dfac_tab, out_e, P, mol_shift);
    }
}

// Round 4
// 250.829 us; speedup vs baseline: 1.0105x; 1.0105x over previous
//
#include <hip/hip_runtime.h>
#include <math.h>

// EnergySRB, R9: inline-asm load pipeline the compiler CANNOT undo.
// R6/R7/R8 post-mortem: every C++-level prefetch was rematerialized away
// (VGPR stuck at 24-28, loads re-serialized at use sites). Meanwhile a
// rocprof replay pass with L2/L3-warm data (near-zero FETCH) still took
// 83us -> not HBM-bound; per-wave load serialization vs ~3K-cycle loaded
// latency is the wall (197K cyc / 64 wave-iters per SIMD).
// R9: 3 x global_load_dwordx4 per group issued via asm volatile (saddr +
// 32-bit voffset), modulo-3 unrolled depth-2 software pipeline, counted
// s_waitcnt vmcnt(6) (never 0 in steady state), sched_barrier(0) after
// each wait (rule #18). 9 loads/wave guaranteed in flight.
// Math bit-identical. LDS exactly 80KB -> 2 blocks/CU kept.

#define NT        1024
#define NBLK      512
#define SCALE_F   134217728.0f              // 2^27
#define INV_SCALE 7.450580596923828125e-9   // 2^-27, exact in double

typedef unsigned v4u __attribute__((ext_vector_type(4)));
typedef float    v4f __attribute__((ext_vector_type(4)));

// ---------------------------------------------------------------------------
// pack species (values 0..3) into 2-bit words. 262144 atoms -> 64KB.
__global__ void pack_species_kernel(const int* __restrict__ sp,
                                    unsigned* __restrict__ packed, int nwords) {
    int w = blockIdx.x * blockDim.x + threadIdx.x;
    if (w >= nwords) return;
    const int4* p4 = (const int4*)(sp + (w << 4));
    int4 a = p4[0], b = p4[1], c = p4[2], d = p4[3];
    unsigned v =
        (unsigned)(a.x & 3)        | ((unsigned)(a.y & 3) << 2)  |
        ((unsigned)(a.z & 3) << 4) | ((unsigned)(a.w & 3) << 6)  |
        ((unsigned)(b.x & 3) << 8) | ((unsigned)(b.y & 3) << 10) |
        ((unsigned)(b.z & 3) << 12)| ((unsigned)(b.w & 3) << 14) |
        ((unsigned)(c.x & 3) << 16)| ((unsigned)(c.y & 3) << 18) |
        ((unsigned)(c.z & 3) << 20)| ((unsigned)(c.w & 3) << 22) |
        ((unsigned)(d.x & 3) << 24)| ((unsigned)(d.y & 3) << 26) |
        ((unsigned)(d.z & 3) << 28)| ((unsigned)(d.w & 3) << 30);
    packed[w] = v;
}

// ---------------------------------------------------------------------------
__global__ void init_kernel(const int* __restrict__ species,
                            float* __restrict__ out,
                            unsigned long long* __restrict__ acc,
                            int n_species, int n_mol) {
    int i = blockIdx.x * blockDim.x + threadIdx.x;
    if (i < n_species) out[i] = (float)species[i];
    if (i < n_mol)     acc[i] = 0ull;
}

// ---------------------------------------------------------------------------
// asm helpers: 3 coupled 16B loads (one 32-bit voffset, three SGPR bases),
// counted waits. Volatile => compiler cannot sink/remat/reorder them.
#define GLOAD(d0, d1, dd, OFF)                                              \
    asm volatile("global_load_dwordx4 %0, %3, %4\n\t"                        \
                 "global_load_dwordx4 %1, %3, %5\n\t"                        \
                 "global_load_dwordx4 %2, %3, %6"                            \
                 : "=&v"(d0), "=&v"(d1), "=&v"(dd)                           \
                 : "v"(OFF), "s"(pb0), "s"(pb1), "s"(pbd)                    \
                 : "memory")

#define VWAIT(n)                                                             \
    do {                                                                     \
        asm volatile("s_waitcnt vmcnt(" #n ")" ::: "memory");                \
        __builtin_amdgcn_sched_barrier(0);                                   \
    } while (0)

// ---------------------------------------------------------------------------
// Pipelined fused kernel. Requires: P%4==0, ng % (grid threads)==0,
// nit >= 2, nit % 3 == 2 (launcher gates). Bench: nit = 8.
__global__ __launch_bounds__(NT, 8)
void srb_fused_u32_pipe(const unsigned* __restrict__ packed_ws,
                        const int* __restrict__ ai,     // [2, P]
                        const float* __restrict__ dist, // [P] angstrom
                        const float* __restrict__ pre_tab,
                        const float* __restrict__ dfac_tab,
                        unsigned long long* __restrict__ acc,
                        int P, int mol_shift, int nit) {
    __shared__ unsigned packed[16384]; // 64KB
    __shared__ unsigned binsu[4096];   // 16KB  (total exactly 80KB)

    const int t = threadIdx.x;
    for (int i = t; i < 4096; i += NT) binsu[i] = 0u;

    const float myPre  = -pre_tab[t & 15];   // magnitude, > 0
    const float myDfac =  dfac_tab[t & 15];

    {
        int4* dst = (int4*)packed;
        const int4* src = (const int4*)packed_ws;
        for (int i = t; i < 4096; i += NT) dst[i] = src[i];
    }
    __syncthreads();

    const float a2b   = (float)1.8897261258369282;
    const float rc    = (float)(5.2 * 1.8897261258369282);
    const float rcinv = (float)(1.0 / (5.2 * 1.8897261258369282));

    const int      stride = (int)gridDim.x * NT;
    const unsigned stepB  = (unsigned)stride * 16u;
    unsigned off = (unsigned)((int)blockIdx.x * NT + t) * 16u;

    const char* pb0 = (const char*)ai;            // a0 rows
    const char* pb1 = (const char*)(ai + P);      // a1 rows
    const char* pbd = (const char*)dist;          // distances

    // body: consumes one 4-pair buffer (math bit-identical to R6/R7/R8)
    #define PBODY(X0, X1, XD)                                                \
    do {                                                                     \
        unsigned a0_[4] = { X0[0], X0[1], X0[2], X0[3] };                    \
        unsigned a1_[4] = { X1[0], X1[1], X1[2], X1[3] };                    \
        float    dd_[4] = { XD[0], XD[1], XD[2], XD[3] };                    \
        unsigned w0_[4], w1_[4];                                             \
        _Pragma("unroll")                                                    \
        for (int k = 0; k < 4; ++k) w0_[k] = packed[a0_[k] >> 4];            \
        _Pragma("unroll")                                                    \
        for (int k = 0; k < 4; ++k) w1_[k] = packed[a1_[k] >> 4];            \
        float pr_[4], df_[4];                                                \
        _Pragma("unroll")                                                    \
        for (int k = 0; k < 4; ++k) {                                        \
            unsigned s0 = (w0_[k] >> ((a0_[k] & 15u) << 1)) & 3u;            \
            unsigned s1 = (w1_[k] >> ((a1_[k] & 15u) << 1)) & 3u;            \
            int idx = (int)((s0 << 2) | s1);                                 \
            pr_[k] = __shfl(myPre,  idx, 64);                                \
            df_[k] = __shfl(myDfac, idx, 64);                                \
        }                                                                    \
        unsigned q_[4];                                                      \
        _Pragma("unroll")                                                    \
        for (int k = 0; k < 4; ++k) {                                        \
            float db  = dd_[k] * a2b;                                        \
            float x   = db * rcinv;                                          \
            float arg = df_[k] * db + (1.0f - 1.0f / (1.0f - x * x));        \
            float mag = pr_[k] * __expf(arg);                                \
            mag = (db < rc) ? mag : 0.0f;                                    \
            q_[k] = (unsigned)(mag * SCALE_F);                               \
        }                                                                    \
        _Pragma("unroll")                                                    \
        for (int k = 0; k < 4; ++k)                                          \
            atomicAdd(&binsu[a0_[k] >> mol_shift], q_[k]);                   \
    } while (0)

    v4u A0, A1, B0, B1, C0, C1;
    v4f AD, BDv, CD;

    // prologue: 2 buffers in flight (6 outstanding loads). nit >= 2.
    GLOAD(A0, A1, AD, off);  off += stepB;
    GLOAD(B0, B1, BDv, off); off += stepB;

    // steady state: 3 iterations per trip, 9 loads outstanding, waits
    // counted at vmcnt(6) so 6 newest always stay in flight.
    int i = 0;
    #pragma unroll 1
    for (; i + 4 < nit; i += 3) {
        GLOAD(C0, C1, CD, off);  off += stepB;
        VWAIT(6);
        PBODY(A0, A1, AD);
        GLOAD(A0, A1, AD, off);  off += stepB;
        VWAIT(6);
        PBODY(B0, B1, BDv);
        GLOAD(B0, B1, BDv, off); off += stepB;
        VWAIT(6);
        PBODY(C0, C1, CD);
    }
    // epilogue (nit % 3 == 2): A, B in flight.
    VWAIT(3);
    PBODY(A0, A1, AD);
    VWAIT(0);
    PBODY(B0, B1, BDv);

    #undef PBODY

    __syncthreads();
    for (int i2 = t; i2 < 4096; i2 += NT) {
        unsigned v = binsu[i2];
        if (v) atomicAdd(&acc[i2], (unsigned long long)v);
    }
}

// ---------------------------------------------------------------------------
// General (non-conforming sizes) fused kernel - R8 code, correct for any P%4==0.
__global__ __launch_bounds__(NT, 8)
void srb_fused_u32_gen(const unsigned* __restrict__ packed_ws,
                       const int* __restrict__ ai,
                       const float* __restrict__ dist,
                       const float* __restrict__ pre_tab,
                       const float* __restrict__ dfac_tab,
                       unsigned long long* __restrict__ acc,
                       int P, int mol_shift) {
    __shared__ unsigned packed[16384];
    __shared__ unsigned binsu[4096];

    const int t = threadIdx.x;
    for (int i = t; i < 4096; i += NT) binsu[i] = 0u;
    const float myPre  = -pre_tab[t & 15];
    const float myDfac =  dfac_tab[t & 15];
    {
        int4* dst = (int4*)packed;
        const int4* src = (const int4*)packed_ws;
        for (int i = t; i < 4096; i += NT) dst[i] = src[i];
    }
    __syncthreads();

    const float a2b   = (float)1.8897261258369282;
    const float rc    = (float)(5.2 * 1.8897261258369282);
    const float rcinv = (float)(1.0 / (5.2 * 1.8897261258369282));

    const int ng     = P >> 2;
    const int stride = (int)gridDim.x * NT;
    const int4*   v0 = (const int4*)ai;
    const int4*   v1 = (const int4*)(ai + P);
    const float4* dv = (const float4*)dist;

    for (int g = (int)blockIdx.x * NT + t; g < ng; g += stride) {
        int4 I0 = v0[g], I1 = v1[g]; float4 D = dv[g];
        unsigned a0[4] = { (unsigned)I0.x, (unsigned)I0.y,
                           (unsigned)I0.z, (unsigned)I0.w };
        unsigned a1[4] = { (unsigned)I1.x, (unsigned)I1.y,
                           (unsigned)I1.z, (unsigned)I1.w };
        float    dd[4] = { D.x, D.y, D.z, D.w };
        unsigned w0[4], w1[4];
        #pragma unroll
        for (int k = 0; k < 4; ++k) w0[k] = packed[a0[k] >> 4];
        #pragma unroll
        for (int k = 0; k < 4; ++k) w1[k] = packed[a1[k] >> 4];
        float pr[4], df[4];
        #pragma unroll
        for (int k = 0; k < 4; ++k) {
            unsigned s0 = (w0[k] >> ((a0[k] & 15u) << 1)) & 3u;
            unsigned s1 = (w1[k] >> ((a1[k] & 15u) << 1)) & 3u;
            int idx = (int)((s0 << 2) | s1);
            pr[k] = __shfl(myPre,  idx, 64);
            df[k] = __shfl(myDfac, idx, 64);
        }
        unsigned q[4];
        #pragma unroll
        for (int k = 0; k < 4; ++k) {
            float db  = dd[k] * a2b;
            float x   = db * rcinv;
            float arg = df[k] * db + (1.0f - 1.0f / (1.0f - x * x));
            float mag = pr[k] * __expf(arg);
            mag = (db < rc) ? mag : 0.0f;
            q[k] = (unsigned)(mag * SCALE_F);
        }
        #pragma unroll
        for (int k = 0; k < 4; ++k)
            atomicAdd(&binsu[a0[k] >> mol_shift], q[k]);
    }

    __syncthreads();
    for (int i = t; i < 4096; i += NT) {
        unsigned v = binsu[i];
        if (v) atomicAdd(&acc[i], (unsigned long long)v);
    }
}

// ---------------------------------------------------------------------------
__global__ void final_kernel(const unsigned long long* __restrict__ acc,
                             const float* __restrict__ energies,
                             float* __restrict__ out_e, int n_mol) {
    int m = blockIdx.x * blockDim.x + threadIdx.x;
    if (m < n_mol)
        out_e[m] = energies[m] - (float)((double)acc[m] * INV_SCALE);
}

// ---------------------------------------------------------------------------
__global__ void init_out_fallback(const int* __restrict__ species,
                                  const float* __restrict__ energies,
                                  float* __restrict__ out,
                                  int n_species, int n_mol) {
    int i = blockIdx.x * blockDim.x + threadIdx.x;
    if (i < n_species) out[i] = (float)species[i];
    else if (i < n_species + n_mol) out[i] = energies[i - n_species];
}

__global__ __launch_bounds__(NT, 1)
void srb_fused_f32(const int* __restrict__ species,
                   const int* __restrict__ ai,
                   const float* __restrict__ dist,
                   const float* __restrict__ pre_tab,
                   const float* __restrict__ dfac_tab,
                   float* __restrict__ out_e,
                   int P, int mol_shift) {
    __shared__ unsigned packed[16384];
    __shared__ float bins[4096];
    __shared__ float2 tab[16];
    const int t = threadIdx.x;
    for (int i = t; i < 4096; i += NT) bins[i] = 0.0f;
    if (t < 16) tab[t] = make_float2(pre_tab[t], dfac_tab[t]);
    for (int w = t; w < 16384; w += NT) {
        const int4* p4 = (const int4*)(species + (w << 4));
        int4 a = p4[0], b = p4[1], c = p4[2], d = p4[3];
        unsigned v =
            (unsigned)(a.x & 3)        | ((unsigned)(a.y & 3) << 2)  |
            ((unsigned)(a.z & 3) << 4) | ((unsigned)(a.w & 3) << 6)  |
            ((unsigned)(b.x & 3) << 8) | ((unsigned)(b.y & 3) << 10) |
            ((unsigned)(b.z & 3) << 12)| ((unsigned)(b.w & 3) << 14) |
            ((unsigned)(c.x & 3) << 16)| ((unsigned)(c.y & 3) << 18) |
            ((unsigned)(c.z & 3) << 20)| ((unsigned)(c.w & 3) << 22) |
            ((unsigned)(d.x & 3) << 24)| ((unsigned)(d.y & 3) << 26) |
            ((unsigned)(d.z & 3) << 28)| ((unsigned)(d.w & 3) << 30);
        packed[w] = v;
    }
    __syncthreads();
    const float a2b   = (float)1.8897261258369282;
    const float rc    = (float)(5.2 * 1.8897261258369282);
    const float rcinv = (float)(1.0 / (5.2 * 1.8897261258369282));
    auto body = [&](int a0, int a1, float dang) {
        unsigned ua0 = (unsigned)a0, ua1 = (unsigned)a1;
        unsigned s0 = (packed[ua0 >> 4] >> ((ua0 & 15u) << 1)) & 3u;
        unsigned s1 = (packed[ua1 >> 4] >> ((ua1 & 15u) << 1)) & 3u;
        float2 td = tab[(s0 << 2) | s1];
        float db = dang * a2b;
        float x  = db * rcinv;
        float arg = td.y * db + (1.0f - 1.0f / (1.0f - x * x));
        float srb = td.x * __expf(arg);
        srb = (db < rc) ? srb : 0.0f;
        atomicAdd(&bins[ua0 >> mol_shift], srb);
    };
    const int nv = P >> 2, stride = (int)gridDim.x * NT;
    const int4* v0 = (const int4*)ai;
    const int4* v1 = (const int4*)(ai + P);
    const float4* dv = (const float4*)dist;
    for (int v = (int)blockIdx.x * NT + t; v < nv; v += stride) {
        int4 i0 = v0[v]; int4 i1 = v1[v]; float4 dd = dv[v];
        body(i0.x, i1.x, dd.x); body(i0.y, i1.y, dd.y);
        body(i0.z, i1.z, dd.z); body(i0.w, i1.w, dd.w);
    }
    __syncthreads();
    for (int i = t; i < 4096; i += NT) {
        float s = bins[i];
        if (s != 0.0f) atomicAdd(&out_e[i], s);
    }
}

// ---------------------------------------------------------------------------
extern "C" void kernel_launch(void* const* d_in, const int* in_sizes, int n_in,
                              void* d_out, int out_size, void* d_ws, size_t ws_size,
                              hipStream_t stream) {
    const int*   species  = (const int*)d_in[0];
    const float* energies = (const float*)d_in[1];
    const int*   ai       = (const int*)d_in[2];
    const float* dist     = (const float*)d_in[3];
    const float* pre_tab  = (const float*)d_in[4];
    const float* dfac_tab = (const float*)d_in[5];

    const int n_species = in_sizes[0];            // 262144
    const int n_mol     = in_sizes[1];            // 4096
    const int P         = in_sizes[3];            // 16777216
    const int n_atoms   = n_species / n_mol;      // 64

    int mol_shift = 0;
    while ((1 << mol_shift) < n_atoms) ++mol_shift; // 6

    float* out   = (float*)d_out;
    float* out_e = out + n_species;

    const int    nwords    = n_species / 16;              // 16384
    const size_t packed_sz = (size_t)nwords * 4;          // 64KB
    const size_t acc_sz    = (size_t)n_mol * 8;           // 32KB
    const size_t need      = packed_sz + acc_sz;

    if (ws_size >= need && (P & 3) == 0) {
        unsigned*           packed = (unsigned*)d_ws;
        unsigned long long* acc    = (unsigned long long*)((char*)d_ws + packed_sz);

        init_kernel<<<(n_species + 255) / 256, 256, 0, stream>>>(
            species, out, acc, n_species, n_mol);
        pack_species_kernel<<<(nwords + 255) / 256, 256, 0, stream>>>(
            species, packed, nwords);

        const int ng     = P >> 2;
        const int stride = NBLK * NT;                     // 524288
        const int nit    = ng / stride;                   // 8 on bench
        const bool pipe_ok = (ng % stride == 0) && (nit >= 2) && (nit % 3 == 2);

        if (pipe_ok) {
            srb_fused_u32_pipe<<<NBLK, NT, 0, stream>>>(
                packed, ai, dist, pre_tab, dfac_tab, acc, P, mol_shift, nit);
        } else {
            srb_fused_u32_gen<<<NBLK, NT, 0, stream>>>(
                packed, ai, dist, pre_tab, dfac_tab, acc, P, mol_shift);
        }
        final_kernel<<<(n_mol + 255) / 256, 256, 0, stream>>>(
            acc, energies, out_e, n_mol);
    } else {
        init_out_fallback<<<(n_species + n_mol + 255) / 256, 256, 0, stream>>>(
            species, energies, out, n_species, n_mol);
        srb_fused_f32<<<NBLK, NT, 0, stream>>>(
            species, ai, dist, pre_tab, dfac_tab, out_e, P, mol_shift);
    }
}